// Round 4
// baseline (61.517 us; speedup 1.0000x reference)
//
#include <hip/hip_runtime.h>
#include <math.h>

#define BSZ 4
#define LEN_M 256
#define LEN_E 512
#define HDIM 512
#define KDIM 512
#define VOCAB 32000

typedef __attribute__((ext_vector_type(8))) short bf16x8;
typedef __attribute__((ext_vector_type(4))) float f32x4;

__device__ inline ushort f2bf(float x) {
    union { float f; unsigned u; } v; v.f = x;
    unsigned r = v.u + 0x7FFFu + ((v.u >> 16) & 1u);   // RNE
    return (ushort)(r >> 16);
}

// load 8 contiguous elements as bf16x8; F32 sources are converted on the fly
template<bool F32>
__device__ inline bf16x8 load8(const char* p) {
    if constexpr (F32) {
        const float4 v0 = ((const float4*)p)[0];
        const float4 v1 = ((const float4*)p)[1];
        bf16x8 r;
        r[0] = (short)f2bf(v0.x); r[1] = (short)f2bf(v0.y);
        r[2] = (short)f2bf(v0.z); r[3] = (short)f2bf(v0.w);
        r[4] = (short)f2bf(v1.x); r[5] = (short)f2bf(v1.y);
        r[6] = (short)f2bf(v1.z); r[7] = (short)f2bf(v1.w);
        return r;
    } else {
        return *(const bf16x8*)p;
    }
}

// ---- C[M][N] = scale * A[M][K] @ B[N][K]^T; bf16 MFMA; fp32 inputs staged ----
// 64x64 tile, 4 waves (2x2), each wave 32x32 = 2x2 frags of 16x16x32 MFMA.
// LROW=72 ushorts (144 B): 16B-aligned b128 ops, lanes spread over disjoint
// 4-bank groups -> at the wave64/b128 8-cycle floor (no extra conflicts).
#define LROW 72
template<bool A32, bool B32, bool OUT_BF16>
__global__ __launch_bounds__(256) void gemm_bt(const void* __restrict__ A,
                                               const void* __restrict__ B,
                                               void* __restrict__ C, int N,
                                               long sA, long sB, long sC,
                                               float scale) {
    __shared__ ushort As[64 * LROW];
    __shared__ ushort Bs[64 * LROW];
    const int t  = threadIdx.x;
    const int m0 = blockIdx.y * 64, n0 = blockIdx.x * 64;
    const size_t bz = blockIdx.z;
    const char* Ab = (const char*)A + bz * (size_t)sA * (A32 ? 4 : 2);
    const char* Bb = (const char*)B + bz * (size_t)sB * (B32 ? 4 : 2);

    const int wid = t >> 6, lane = t & 63;
    const int wr = wid >> 1, wc = wid & 1;
    const int lrow = lane & 15, lk = (lane >> 4) * 8;

    const int r0 = t >> 3;          // staging rows r0 and r0+32
    const int c8 = (t & 7) * 8;     // 8-element k-chunk

    bf16x8 pa0, pa1, pb0, pb1;
    f32x4 acc[2][2] = {};

    // prologue: K-tile 0
    pa0 = load8<A32>(Ab + ((size_t)(m0 + r0)      * KDIM + c8) * (A32 ? 4 : 2));
    pa1 = load8<A32>(Ab + ((size_t)(m0 + r0 + 32) * KDIM + c8) * (A32 ? 4 : 2));
    pb0 = load8<B32>(Bb + ((size_t)(n0 + r0)      * KDIM + c8) * (B32 ? 4 : 2));
    pb1 = load8<B32>(Bb + ((size_t)(n0 + r0 + 32) * KDIM + c8) * (B32 ? 4 : 2));
    *(bf16x8*)&As[(r0)      * LROW + c8] = pa0;
    *(bf16x8*)&As[(r0 + 32) * LROW + c8] = pa1;
    *(bf16x8*)&Bs[(r0)      * LROW + c8] = pb0;
    *(bf16x8*)&Bs[(r0 + 32) * LROW + c8] = pb1;
    __syncthreads();

    for (int kt = 0; kt < KDIM / 64; ++kt) {
        if (kt + 1 < KDIM / 64) {           // prefetch next K-tile into regs
            const int k0 = (kt + 1) * 64;
            pa0 = load8<A32>(Ab + ((size_t)(m0 + r0)      * KDIM + k0 + c8) * (A32 ? 4 : 2));
            pa1 = load8<A32>(Ab + ((size_t)(m0 + r0 + 32) * KDIM + k0 + c8) * (A32 ? 4 : 2));
            pb0 = load8<B32>(Bb + ((size_t)(n0 + r0)      * KDIM + k0 + c8) * (B32 ? 4 : 2));
            pb1 = load8<B32>(Bb + ((size_t)(n0 + r0 + 32) * KDIM + k0 + c8) * (B32 ? 4 : 2));
        }
#pragma unroll
        for (int ks = 0; ks < 2; ++ks) {
            bf16x8 af[2], bfr[2];
#pragma unroll
            for (int i = 0; i < 2; ++i)
                af[i]  = *(const bf16x8*)&As[(wr * 32 + i * 16 + lrow) * LROW + ks * 32 + lk];
#pragma unroll
            for (int j = 0; j < 2; ++j)
                bfr[j] = *(const bf16x8*)&Bs[(wc * 32 + j * 16 + lrow) * LROW + ks * 32 + lk];
#pragma unroll
            for (int i = 0; i < 2; ++i)
#pragma unroll
                for (int j = 0; j < 2; ++j)
                    acc[i][j] = __builtin_amdgcn_mfma_f32_16x16x32_bf16(af[i], bfr[j], acc[i][j], 0, 0, 0);
        }
        __syncthreads();
        if (kt + 1 < KDIM / 64) {
            *(bf16x8*)&As[(r0)      * LROW + c8] = pa0;
            *(bf16x8*)&As[(r0 + 32) * LROW + c8] = pa1;
            *(bf16x8*)&Bs[(r0)      * LROW + c8] = pb0;
            *(bf16x8*)&Bs[(r0 + 32) * LROW + c8] = pb1;
            __syncthreads();
        }
    }

    // epilogue: C/D layout (m89): col = lane&15, row = (lane>>4)*4 + reg
    const int crow = m0 + wr * 32 + (lane >> 4) * 4;
    const int ccol = n0 + wc * 32 + lrow;
#pragma unroll
    for (int i = 0; i < 2; ++i)
#pragma unroll
        for (int j = 0; j < 2; ++j)
#pragma unroll
            for (int r = 0; r < 4; ++r) {
                const size_t o = bz * (size_t)sC + (size_t)(crow + i * 16 + r) * N + ccol + j * 16;
                const float v = acc[i][j][r] * scale;
                if (OUT_BF16) ((ushort*)C)[o] = f2bf(v);
                else          ((float*)C)[o]  = v;
            }
}

// ---- fused: lambda + dual softmax + zero + scatter + stream half a vocab row --
#define CHUNK 16000          // 64000 B LDS -> 2 blocks/CU (16 waves)
__global__ __launch_bounds__(512) void softmax_distribute(const float* __restrict__ Lg,
                                                          const float* __restrict__ bq,
                                                          const float* __restrict__ bc,
                                                          const float* __restrict__ D,
                                                          const float* __restrict__ Cq,
                                                          const float* __restrict__ Cc,
                                                          const float* __restrict__ Wl,
                                                          const float* __restrict__ bl,
                                                          const int* __restrict__ idx,
                                                          float* __restrict__ out) {
    __shared__ float buf[CHUNK];
    __shared__ float sh[8], smq[8], smc[8], ssq[8], ssc[8];
    const int blk = blockIdx.x;         // 0..2047
    const int bm  = blk >> 1;           // row 0..1023
    const int lo  = (blk & 1) * CHUNK;  // vocab half
    const int b   = bm >> 8;            // LEN_M = 256
    const int e   = threadIdx.x;        // 0..511
    const int wid = e >> 6;

    // zero the LDS chunk (covered by the first __syncthreads below)
    for (int i = e; i < CHUNK / 4; i += 512)
        ((float4*)buf)[i] = make_float4(0.f, 0.f, 0.f, 0.f);

    // lambda partial: sigmoid([D|Cq|Cc] . W_lambda + b)
    const size_t rb = (size_t)bm * HDIM + e;
    float ls = D[rb] * Wl[e] + Cq[rb] * Wl[HDIM + e] + Cc[rb] * Wl[2 * HDIM + e];
#pragma unroll
    for (int o = 32; o; o >>= 1) ls += __shfl_xor(ls, o);
    if ((e & 63) == 0) sh[wid] = ls;

    const float L  = Lg[(size_t)bm * LEN_E + e];
    const float xq = L + bq[b * LEN_E + e];
    const float xc = L + bc[b * LEN_E + e];

    // block max (both softmaxes at once)
    float mq = xq, mc = xc;
#pragma unroll
    for (int o = 32; o; o >>= 1) {
        mq = fmaxf(mq, __shfl_xor(mq, o));
        mc = fmaxf(mc, __shfl_xor(mc, o));
    }
    if ((e & 63) == 0) { smq[wid] = mq; smc[wid] = mc; }
    __syncthreads();
    float lsum = sh[0];
    mq = smq[0]; mc = smc[0];
#pragma unroll
    for (int i = 1; i < 8; ++i) {
        lsum += sh[i];
        mq = fmaxf(mq, smq[i]); mc = fmaxf(mc, smc[i]);
    }
    const float lam = 1.f / (1.f + expf(-(lsum + bl[0])));

    // exp + block sum
    const float pq = expf(xq - mq);
    const float pc = expf(xc - mc);
    float sq = pq, sc = pc;
#pragma unroll
    for (int o = 32; o; o >>= 1) {
        sq += __shfl_xor(sq, o);
        sc += __shfl_xor(sc, o);
    }
    if ((e & 63) == 0) { ssq[wid] = sq; ssc[wid] = sc; }
    __syncthreads();
    sq = ssq[0]; sc = ssc[0];
#pragma unroll
    for (int i = 1; i < 8; ++i) { sq += ssq[i]; sc += ssc[i]; }

    // scatter (LDS atomics resolve duplicate token ids within the chunk)
    const float val = lam * (pq / sq) + (1.f - lam) * (pc / sc);
    const int v = idx[b * LEN_E + e] - lo;
    if ((unsigned)v < (unsigned)CHUNK) atomicAdd(&buf[v], val);
    __syncthreads();

    // stream the chunk to global (pure float4 stores)
    float4* __restrict__ dst = (float4*)(out + (size_t)bm * VOCAB + lo);
    for (int i = e; i < CHUNK / 4; i += 512)
        dst[i] = ((const float4*)buf)[i];
}

extern "C" void kernel_launch(void* const* d_in, const int* in_sizes, int n_in,
                              void* d_out, int out_size, void* d_ws, size_t ws_size,
                              hipStream_t stream) {
    const int*   idx = (const int*)  d_in[0];
    const float* D   = (const float*)d_in[1];
    const float* Cq  = (const float*)d_in[2];
    const float* Cc  = (const float*)d_in[3];
    const float* Mm  = (const float*)d_in[4];
    const float* E   = (const float*)d_in[5];
    const float* bq  = (const float*)d_in[6];
    const float* bc  = (const float*)d_in[7];
    const float* Wl  = (const float*)d_in[8];
    const float* bl  = (const float*)d_in[9];
    const float* We  = (const float*)d_in[10];
    const float* Wm  = (const float*)d_in[11];
    float* out = (float*)d_out;

    // workspace (16B aligned)
    char* w = (char*)d_ws;
    ushort* W2T = (ushort*)w;  w += (size_t)512 * 512 * 2;    // (We @ Wm^T) * s, bf16
    ushort* T1  = (ushort*)w;  w += (size_t)1024 * 512 * 2;   // M @ W2T^T, bf16
    float*  Lg  = (float*)w;                                  // logits, fp32

    // 1) W2T = (We @ Wm^T) * H^-0.5        [512 x 512]
    gemm_bt<true, true, true><<<dim3(8, 8, 1), 256, 0, stream>>>(
        We, Wm, W2T, 512, 0, 0, 0, 0.04419417382415922f);
    // 2) T1 = M @ W2T^T                    [1024 x 512]
    gemm_bt<true, false, true><<<dim3(8, 16, 1), 256, 0, stream>>>(
        Mm, W2T, T1, 512, 0, 0, 0, 1.0f);
    // 3) logits[b] = T1[b] @ E[b]^T        [4 x 256 x 512]
    gemm_bt<false, true, false><<<dim3(8, 4, BSZ), 256, 0, stream>>>(
        T1, E, Lg, 512, 256 * 512, 512 * 512, 256 * 512, 1.0f);
    // 4) fused lambda + dual softmax + zero + scatter + stream
    softmax_distribute<<<2048, 512, 0, stream>>>(
        Lg, bq, bc, D, Cq, Cc, Wl, bl, idx, out);
}